// Round 1
// 732.022 us; speedup vs baseline: 1.0025x; 1.0025x over previous
//
#include <hip/hip_runtime.h>
#include <math.h>

#define NN   50000
#define NE   800000
#define ESL  (NE + NN)     // CSR slots incl. one self-loop per node
#define DIN1 128
#define DE   16
#define C    64
#define HID  256
#define DCLS 144
#define KP   160      // DCLS padded to multiple of 32
#define LDA  168      // LDS row stride (bf16 elems), multiple of 8 for 16B align
#define NEGS 0.2f
#define NPB  8
#define NBLK ((NN + 255) / 256)   // 196 scan blocks

typedef __attribute__((ext_vector_type(8))) short  short8;   // 8 bf16 in 4 VGPRs
typedef __attribute__((ext_vector_type(4))) float  f32x4;

// float -> bf16 (RNE)
__device__ __forceinline__ ushort f2bf(float f) {
    unsigned u = __float_as_uint(f);
    u += 0x7fffu + ((u >> 16) & 1u);
    return (ushort)(u >> 16);
}
__device__ __forceinline__ float bf2f(ushort u) {
    return __uint_as_float(((unsigned)u) << 16);
}
// packed bf16 pair -> two floats (1 op each)
__device__ __forceinline__ float bflo(unsigned w) { return __uint_as_float(w << 16); }
__device__ __forceinline__ float bfhi(unsigned w) { return __uint_as_float(w & 0xffff0000u); }

// ---- degree histogram ----
__global__ void k_deg(const int* __restrict__ dst, int* __restrict__ deg) {
    int e = blockIdx.x * blockDim.x + threadIdx.x;
    if (e < NE) atomicAdd(&deg[dst[e]], 1);
}

// ---- CSR build: scan of (deg+1) -> rowptr (self-loop slot per node) ----
__global__ void k_scan1(const int* __restrict__ deg, int* __restrict__ rowptr,
                        int* __restrict__ bsum) {
    __shared__ int s[256];
    int t = threadIdx.x;
    int i = blockIdx.x * 256 + t;
    int v = (i < NN) ? (deg[i] + 1) : 0;
    s[t] = v;
    __syncthreads();
    for (int off = 1; off < 256; off <<= 1) {
        int u = (t >= off) ? s[t - off] : 0;
        __syncthreads();
        s[t] += u;
        __syncthreads();
    }
    if (i < NN) rowptr[i] = s[t] - v;          // exclusive
    if (t == 255) bsum[blockIdx.x] = s[255];
}

__global__ void k_scan2(int* __restrict__ bsum, int* __restrict__ boff) {
    __shared__ int s[256];
    int t = threadIdx.x;
    int v = (t < NBLK) ? bsum[t] : 0;
    s[t] = v;
    __syncthreads();
    for (int off = 1; off < 256; off <<= 1) {
        int u = (t >= off) ? s[t - off] : 0;
        __syncthreads();
        s[t] += u;
        __syncthreads();
    }
    if (t < NBLK) boff[t] = s[t] - v;          // exclusive
}

__global__ void k_scan3(int* __restrict__ rowptr, const int* __restrict__ boff) {
    int i = blockIdx.x * 256 + threadIdx.x;
    if (i < NN) rowptr[i] += boff[blockIdx.x];
    if (i == 0) rowptr[NN] = ESL;
}

// ---- scatter: permute src + edge_attr(bf16) into CSR order ----
__global__ void k_scatter(const int* __restrict__ src, const int* __restrict__ dst,
                          const float* __restrict__ eattr,
                          const int* __restrict__ rowptr, int* __restrict__ cursor,
                          int* __restrict__ src_perm, ushort* __restrict__ eap) {
    int e = blockIdx.x * blockDim.x + threadIdx.x;
    if (e >= NE) return;
    int d = dst[e];
    int pos = atomicAdd(&cursor[d], 1);
    int idx = rowptr[d] + pos;
    src_perm[idx] = src[e];
    const float4* p4 = (const float4*)&eattr[(size_t)e * DE];
    float4 c0 = p4[0], c1 = p4[1], c2 = p4[2], c3 = p4[3];
    short8 r0, r1;
    r0[0]=f2bf(c0.x); r0[1]=f2bf(c0.y); r0[2]=f2bf(c0.z); r0[3]=f2bf(c0.w);
    r0[4]=f2bf(c1.x); r0[5]=f2bf(c1.y); r0[6]=f2bf(c1.z); r0[7]=f2bf(c1.w);
    r1[0]=f2bf(c2.x); r1[1]=f2bf(c2.y); r1[2]=f2bf(c2.z); r1[3]=f2bf(c2.w);
    r1[4]=f2bf(c3.x); r1[5]=f2bf(c3.y); r1[6]=f2bf(c3.z); r1[7]=f2bf(c3.w);
    short8* q = (short8*)&eap[(size_t)idx * DE];
    q[0] = r0; q[1] = r1;
}

// ---- self-loop mean attr -> written into the CSR self slot ----
__global__ void k_loop_csr(const int* __restrict__ rowptr,
                           ushort* __restrict__ eap, int* __restrict__ src_perm) {
    int wave = threadIdx.x >> 6, lane = threadIdx.x & 63;
    int d = blockIdx.x * 4 + wave;
    if (d >= NN) return;
    int j = lane & 15, g = lane >> 4;
    int kb = rowptr[d], ke1 = rowptr[d + 1] - 1;   // real edges in [kb, ke1)
    float sum = 0.f;
    for (int k = kb + g; k < ke1; k += 4)
        sum += bf2f(eap[(size_t)k * DE + j]);
    sum += __shfl_xor(sum, 16);
    sum += __shfl_xor(sum, 32);
    if (lane < 16)
        eap[(size_t)ke1 * DE + lane] = f2bf(sum / fmaxf((float)(ke1 - kb), 1.0f));
    if (lane == 16) src_perm[ke1] = d;
}

// ---- node linear transforms: xl(bf16) = x@Wl+bl, xr(fp32) = x@Wr+br ----
template<int DINT>
__global__ void k_lin(const float* __restrict__ x,
                      const float* __restrict__ Wl, const float* __restrict__ bl,
                      const float* __restrict__ Wr, const float* __restrict__ br,
                      ushort* __restrict__ xlb, float* __restrict__ xr) {
    int i0 = blockIdx.x * NPB;
    int t = threadIdx.x;
    int c = t & (C - 1);
    const float* W = (t < C) ? Wl : Wr;
    float bb = (t < C) ? bl[c] : br[c];
    float acc[NPB];
#pragma unroll
    for (int n = 0; n < NPB; ++n) acc[n] = bb;
    for (int k = 0; k < DINT; ++k) {
        float wk = W[k * C + c];
#pragma unroll
        for (int n = 0; n < NPB; ++n)
            acc[n] = fmaf(x[(i0 + n) * DINT + k], wk, acc[n]);
    }
    if (t < C) {
#pragma unroll
        for (int n = 0; n < NPB; ++n)
            xlb[(size_t)(i0 + n) * C + c] = f2bf(acc[n]);
    } else {
#pragma unroll
        for (int n = 0; n < NPB; ++n)
            xr[(size_t)(i0 + n) * C + c] = acc[n];
    }
}

// ---- fused GAT layer, 4-edge x 16-lane layout ----
// One wave per dst node. lane = g*16+l: group g handles edge k+g, lane l owns
// channels 4l..4l+3. We column-slice (16x4 fp32) lives in 64 VGPRs, loaded once.
// No running-max (softmax shift-invariant, logits << 88).
template<int DO_ELU, int OUT_BF16>
__global__ __launch_bounds__(64, 4) void k_gat(
        const int* __restrict__ src_perm, const int* __restrict__ rowptr,
        const ushort* __restrict__ eap,
        const ushort* __restrict__ xlb, const float* __restrict__ xr,
        const float* __restrict__ We, const float* __restrict__ att,
        const float* __restrict__ bias, void* __restrict__ o_) {
    int d = blockIdx.x;
    int lane = threadIdx.x;
    int g = lane >> 4, l = lane & 15;
    int c0 = l * 4;
    // per-lane We slice: We[j][c0..c0+3], j = 0..15  (64 VGPRs, loop-invariant)
    float wreg[DE][4];
#pragma unroll
    for (int j = 0; j < DE; ++j) {
        float4 wv = *(const float4*)&We[j * C + c0];
        wreg[j][0] = wv.x; wreg[j][1] = wv.y; wreg[j][2] = wv.z; wreg[j][3] = wv.w;
    }
    float4 av4 = *(const float4*)&att[c0];
    float attv[4] = {av4.x, av4.y, av4.z, av4.w};
    float4 xr4 = *(const float4*)&xr[(size_t)d * C + c0];
    float xrv[4] = {xr4.x, xr4.y, xr4.z, xr4.w};

    float l_run = 0.f, n_run[4] = {0.f, 0.f, 0.f, 0.f};
    int kb = rowptr[d], ke = rowptr[d + 1];
    for (int k = kb; k < ke; k += 4) {
        int kk = k + g;
        bool valid = kk < ke;
        int kidx = valid ? kk : (ke - 1);
        int s = src_perm[kidx];
        // xl channels c0..c0+3 (bf16, 8B); 16 lanes cover the full 128B row
        uint2 xlr = *(const uint2*)&xlb[(size_t)s * C + c0];
        float xlv[4] = {bflo(xlr.x), bfhi(xlr.x), bflo(xlr.y), bfhi(xlr.y)};
        // edge attr row (bf16, 32B broadcast within group; groups are seq rows)
        const uint4* ep = (const uint4*)&eap[(size_t)kidx * DE];
        uint4 e0 = ep[0], e1 = ep[1];
        float m[4];
#pragma unroll
        for (int i = 0; i < 4; ++i) m[i] = xlv[i] + xrv[i];
        unsigned ew[8] = {e0.x, e0.y, e0.z, e0.w, e1.x, e1.y, e1.z, e1.w};
#pragma unroll
        for (int wji = 0; wji < 8; ++wji) {
            float elo = bflo(ew[wji]), ehi = bfhi(ew[wji]);
#pragma unroll
            for (int i = 0; i < 4; ++i) {
                m[i] = fmaf(elo, wreg[2 * wji][i], m[i]);
                m[i] = fmaf(ehi, wreg[2 * wji + 1][i], m[i]);
            }
        }
        // leaky_relu + dot with att over this lane's 4 channels
        float p = 0.f;
#pragma unroll
        for (int i = 0; i < 4; ++i) {
            float t = fmaxf(m[i], NEGS * m[i]);   // leaky via max
            p = fmaf(t, attv[i], p);
        }
        // reduce across the 16 lanes of the group
        p += __shfl_xor(p, 1);
        p += __shfl_xor(p, 2);
        p += __shfl_xor(p, 4);
        p += __shfl_xor(p, 8);
        float pe = valid ? __expf(p) : 0.f;
        l_run += pe;
#pragma unroll
        for (int i = 0; i < 4; ++i) n_run[i] = fmaf(pe, xlv[i], n_run[i]);
    }
    // cross-group reduction (4 groups -> total)
    l_run += __shfl_xor(l_run, 16);
    l_run += __shfl_xor(l_run, 32);
#pragma unroll
    for (int i = 0; i < 4; ++i) {
        n_run[i] += __shfl_xor(n_run[i], 16);
        n_run[i] += __shfl_xor(n_run[i], 32);
    }
    if (g == 0) {
        float4 bv = *(const float4*)&bias[c0];
        float bvv[4] = {bv.x, bv.y, bv.z, bv.w};
        float res[4];
#pragma unroll
        for (int i = 0; i < 4; ++i) {
            float v = n_run[i] / l_run + bvv[i];
            if (DO_ELU) v = (v > 0.f) ? v : (__expf(v) - 1.0f);
            res[i] = v;
        }
        if (OUT_BF16) {
            uint2 pk;
            pk.x = (unsigned)f2bf(res[0]) | ((unsigned)f2bf(res[1]) << 16);
            pk.y = (unsigned)f2bf(res[2]) | ((unsigned)f2bf(res[3]) << 16);
            *(uint2*)&((ushort*)o_)[(size_t)d * C + c0] = pk;
        } else {
            float4 pk = {res[0], res[1], res[2], res[3]};
            *(float4*)&((float*)o_)[(size_t)d * C + c0] = pk;
        }
    }
}

// Cw1 [144][256] fp32 -> Cw1T bf16 [256][160] (transpose + zero-pad K)
__global__ void k_cvt_w(const float* __restrict__ Cw1, short* __restrict__ Cw1T) {
    int n = blockIdx.x;
    int k = threadIdx.x;
    Cw1T[n * KP + k] = (k < DCLS) ? (short)f2bf(Cw1[k * HID + n]) : (short)0;
}

// ---- MFMA edge classifier, TRANSPOSED orientation ----
// D[m=hidden][n=edge] = sum_k Cw1T[m][k] * EF[n][k].
// C-layout: col(lane&15) = edge, row(quad*4+reg) = hidden -> the 256-dim
// hidden reduction for layer 2 is lane-local (64 fma) + 2 shuffles + one
// plain LDS store per wave (no atomics, no per-(mt,r) 16-lane reductions).
// Cb1 is folded into the accumulator init (exact fp32).
__global__ __launch_bounds__(256, 4) void k_cls_mfma(
        const int* __restrict__ src, const int* __restrict__ dst,
        const float* __restrict__ eattr, const short* __restrict__ h2b,
        const short* __restrict__ Cw1T, const float* __restrict__ Cb1,
        const float* __restrict__ Cw2, const float* __restrict__ Cb2,
        float* __restrict__ out) {
    __shared__ short sEF[64 * LDA];
    __shared__ float sOutW[4][64];
    int t = threadIdx.x;
    int ebase = blockIdx.x * 64;
    {
        int el = t & 63, part = t >> 6;
        int e = ebase + el;
        short8* q = (short8*)&sEF[el * LDA];
        if (part == 0) {
            const short8* p = (const short8*)&h2b[(size_t)src[e] * C];
#pragma unroll
            for (int i = 0; i < 8; ++i) q[i] = p[i];
        } else if (part == 1) {
            const short8* p = (const short8*)&h2b[(size_t)dst[e] * C];
#pragma unroll
            for (int i = 0; i < 8; ++i) q[8 + i] = p[i];
        } else if (part == 2) {
            const float4* p4 = (const float4*)&eattr[(size_t)e * DE];
            float4 c0 = p4[0], c1 = p4[1], c2 = p4[2], c3 = p4[3];
            short8 r0, r1;
            r0[0]=f2bf(c0.x); r0[1]=f2bf(c0.y); r0[2]=f2bf(c0.z); r0[3]=f2bf(c0.w);
            r0[4]=f2bf(c1.x); r0[5]=f2bf(c1.y); r0[6]=f2bf(c1.z); r0[7]=f2bf(c1.w);
            r1[0]=f2bf(c2.x); r1[1]=f2bf(c2.y); r1[2]=f2bf(c2.z); r1[3]=f2bf(c2.w);
            r1[4]=f2bf(c3.x); r1[5]=f2bf(c3.y); r1[6]=f2bf(c3.z); r1[7]=f2bf(c3.w);
            q[16] = r0; q[17] = r1;
        } else {
            short8 z = {0,0,0,0,0,0,0,0};
            q[18] = z; q[19] = z;
        }
    }
    __syncthreads();

    int lane = t & 63, wave = t >> 6;
    int l15 = lane & 15, quad = lane >> 4;
    int hb = wave * 64;                         // this wave's hidden base

    // bias + layer-2 weights for this lane's 16 hidden rows (r-contiguous)
    float cb1v[4][4], cw2v[4][4];
#pragma unroll
    for (int mt = 0; mt < 4; ++mt) {
        float4 bv = *(const float4*)&Cb1[hb + mt * 16 + quad * 4];
        float4 wv = *(const float4*)&Cw2[hb + mt * 16 + quad * 4];
        cb1v[mt][0] = bv.x; cb1v[mt][1] = bv.y; cb1v[mt][2] = bv.z; cb1v[mt][3] = bv.w;
        cw2v[mt][0] = wv.x; cw2v[mt][1] = wv.y; cw2v[mt][2] = wv.z; cw2v[mt][3] = wv.w;
    }

    f32x4 acc[4][4];
#pragma unroll
    for (int mt = 0; mt < 4; ++mt) {
        f32x4 bi = {cb1v[mt][0], cb1v[mt][1], cb1v[mt][2], cb1v[mt][3]};
#pragma unroll
        for (int nt = 0; nt < 4; ++nt) acc[mt][nt] = bi;   // bias folded into C-init
    }

    const short8* Ap = (const short8*)Cw1T;
#pragma unroll
    for (int kk = 0; kk < 5; ++kk) {
        short8 a[4], b[4];
#pragma unroll
        for (int mt = 0; mt < 4; ++mt)       // A: Cw1T rows = hidden (global, L2-hot)
            a[mt] = Ap[(hb + mt * 16 + l15) * 20 + kk * 4 + quad];
#pragma unroll
        for (int nt = 0; nt < 4; ++nt)       // B: edge features (LDS)
            b[nt] = *(const short8*)&sEF[(nt * 16 + l15) * LDA + kk * 32 + quad * 8];
#pragma unroll
        for (int mt = 0; mt < 4; ++mt)
#pragma unroll
            for (int nt = 0; nt < 4; ++nt)
                acc[mt][nt] = __builtin_amdgcn_mfma_f32_16x16x32_bf16(
                    a[mt], b[nt], acc[mt][nt], 0, 0, 0);
    }

    // layer 2: out[edge] = sum_hid elu(h[hid][edge]) * cw2[hid]  (lane-local fma)
    float p[4] = {0.f, 0.f, 0.f, 0.f};
#pragma unroll
    for (int nt = 0; nt < 4; ++nt)
#pragma unroll
        for (int mt = 0; mt < 4; ++mt)
#pragma unroll
            for (int r = 0; r < 4; ++r) {
                float h = acc[mt][nt][r];                    // bias already in
                float act = (h > 0.f) ? h : (__expf(h) - 1.0f);  // fast elu
                p[nt] = fmaf(act, cw2v[mt][r], p[nt]);
            }
    // sum the 4 quads (hidden sub-ranges) -> full 64-hid partial for this wave
#pragma unroll
    for (int nt = 0; nt < 4; ++nt) {
        p[nt] += __shfl_xor(p[nt], 16);
        p[nt] += __shfl_xor(p[nt], 32);
    }
    if (quad == 0) {
#pragma unroll
        for (int nt = 0; nt < 4; ++nt)
            sOutW[wave][nt * 16 + l15] = p[nt];
    }
    __syncthreads();
    if (t < 64)
        out[ebase + t] = sOutW[0][t] + sOutW[1][t] + sOutW[2][t] + sOutW[3][t] + Cb2[0];
}

extern "C" void kernel_launch(void* const* d_in, const int* in_sizes, int n_in,
                              void* d_out, int out_size, void* d_ws, size_t ws_size,
                              hipStream_t stream) {
    const float* x     = (const float*)d_in[0];
    const float* eattr = (const float*)d_in[1];
    const float* W1l   = (const float*)d_in[2];
    const float* b1l   = (const float*)d_in[3];
    const float* W1r   = (const float*)d_in[4];
    const float* b1r   = (const float*)d_in[5];
    const float* We1   = (const float*)d_in[6];
    const float* att1  = (const float*)d_in[7];
    const float* bias1 = (const float*)d_in[8];
    const float* W2l   = (const float*)d_in[9];
    const float* b2l   = (const float*)d_in[10];
    const float* W2r   = (const float*)d_in[11];
    const float* b2r   = (const float*)d_in[12];
    const float* We2   = (const float*)d_in[13];
    const float* att2  = (const float*)d_in[14];
    const float* bias2 = (const float*)d_in[15];
    // d_in[16..19] (Aw1,Ab1,Aw2,Ab2) dead: softmax over size-1 axis == 1.0
    const float* Cw1   = (const float*)d_in[20];
    const float* Cb1   = (const float*)d_in[21];
    const float* Cw2   = (const float*)d_in[22];
    const float* Cb2   = (const float*)d_in[23];
    const int*   eidx  = (const int*)d_in[24];
    const int* src = eidx;
    const int* dst = eidx + NE;
    float* out = (float*)d_out;

    // workspace layout
    int*    deg      = (int*)d_ws;                     // NN
    int*    cursor   = deg + NN;                       // NN
    int*    rowptr   = cursor + NN;                    // NN+4
    int*    bsum     = rowptr + NN + 4;                // 256
    int*    boff     = bsum + 256;                     // 256
    int*    src_perm = boff + 256;                     // ESL
    ushort* eap      = (ushort*)(src_perm + ESL);      // ESL*16 bf16 (CSR-ordered eattr)
    ushort* xlb      = eap + (size_t)ESL * DE;         // 64NN bf16
    float*  xr       = (float*)(xlb + (size_t)NN * C); // 64NN
    float*  o1       = xr + (size_t)64 * NN;           // 64NN
    short*  h2b      = (short*)(o1 + (size_t)64 * NN); // 64NN bf16
    short*  cw1t     = h2b + (size_t)NN * C;           // 256*160 bf16

    // zero deg + cursor (contiguous)
    hipMemsetAsync(deg, 0, (size_t)(2 * NN) * sizeof(int), stream);

    // CSR build (with one self-loop slot per node)
    k_deg<<<(NE + 255) / 256, 256, 0, stream>>>(dst, deg);
    k_scan1<<<NBLK, 256, 0, stream>>>(deg, rowptr, bsum);
    k_scan2<<<1, 256, 0, stream>>>(bsum, boff);
    k_scan3<<<NBLK, 256, 0, stream>>>(rowptr, boff);
    k_scatter<<<(NE + 255) / 256, 256, 0, stream>>>(src, dst, eattr, rowptr, cursor,
                                                    src_perm, eap);
    k_loop_csr<<<(NN + 3) / 4, 256, 0, stream>>>(rowptr, eap, src_perm);

    // classifier weight conversion (independent)
    k_cvt_w<<<HID, KP, 0, stream>>>(Cw1, cw1t);

    // ---- GAT layer 1 ----
    k_lin<DIN1><<<NN / NPB, 128, 0, stream>>>(x, W1l, b1l, W1r, b1r, xlb, xr);
    k_gat<1, 0><<<NN, 64, 0, stream>>>(src_perm, rowptr, eap, xlb, xr,
                                       We1, att1, bias1, o1);   // -> h (elu, fp32)

    // ---- GAT layer 2 (h2 written directly as bf16) ----
    k_lin<C><<<NN / NPB, 128, 0, stream>>>(o1, W2l, b2l, W2r, b2r, xlb, xr);
    k_gat<0, 1><<<NN, 64, 0, stream>>>(src_perm, rowptr, eap, xlb, xr,
                                       We2, att2, bias2, h2b);  // -> h2 bf16

    // ---- MFMA edge classifier on original edges ----
    k_cls_mfma<<<NE / 64, 256, 0, stream>>>(src, dst, eattr, h2b, cw1t, Cb1, Cw2, Cb2, out);
}

// Round 2
// 724.649 us; speedup vs baseline: 1.0127x; 1.0102x over previous
//
#include <hip/hip_runtime.h>
#include <math.h>

#define NN   50000
#define NE   800000
#define ESL  (NE + NN)     // CSR slots incl. one self-loop per node
#define DIN1 128
#define DE   16
#define C    64
#define HID  256
#define DCLS 144
#define KP   160      // DCLS padded to multiple of 32
#define NEGS 0.2f
#define NPB  8
#define NBLK ((NN + 255) / 256)   // 196 scan blocks

typedef __attribute__((ext_vector_type(8))) short  short8;   // 8 bf16 in 4 VGPRs
typedef __attribute__((ext_vector_type(4))) float  f32x4;

// float -> bf16 (RNE)
__device__ __forceinline__ ushort f2bf(float f) {
    unsigned u = __float_as_uint(f);
    u += 0x7fffu + ((u >> 16) & 1u);
    return (ushort)(u >> 16);
}
__device__ __forceinline__ float bf2f(ushort u) {
    return __uint_as_float(((unsigned)u) << 16);
}
// packed bf16 pair -> two floats (1 op each)
__device__ __forceinline__ float bflo(unsigned w) { return __uint_as_float(w << 16); }
__device__ __forceinline__ float bfhi(unsigned w) { return __uint_as_float(w & 0xffff0000u); }

// ---- degree histogram ----
__global__ void k_deg(const int* __restrict__ dst, int* __restrict__ deg) {
    int e = blockIdx.x * blockDim.x + threadIdx.x;
    if (e < NE) atomicAdd(&deg[dst[e]], 1);
}

// ---- CSR build: scan of (deg+1) -> rowptr (self-loop slot per node) ----
__global__ void k_scan1(const int* __restrict__ deg, int* __restrict__ rowptr,
                        int* __restrict__ bsum) {
    __shared__ int s[256];
    int t = threadIdx.x;
    int i = blockIdx.x * 256 + t;
    int v = (i < NN) ? (deg[i] + 1) : 0;
    s[t] = v;
    __syncthreads();
    for (int off = 1; off < 256; off <<= 1) {
        int u = (t >= off) ? s[t - off] : 0;
        __syncthreads();
        s[t] += u;
        __syncthreads();
    }
    if (i < NN) rowptr[i] = s[t] - v;          // exclusive
    if (t == 255) bsum[blockIdx.x] = s[255];
}

__global__ void k_scan2(int* __restrict__ bsum, int* __restrict__ boff) {
    __shared__ int s[256];
    int t = threadIdx.x;
    int v = (t < NBLK) ? bsum[t] : 0;
    s[t] = v;
    __syncthreads();
    for (int off = 1; off < 256; off <<= 1) {
        int u = (t >= off) ? s[t - off] : 0;
        __syncthreads();
        s[t] += u;
        __syncthreads();
    }
    if (t < NBLK) boff[t] = s[t] - v;          // exclusive
}

__global__ void k_scan3(int* __restrict__ rowptr, const int* __restrict__ boff) {
    int i = blockIdx.x * 256 + threadIdx.x;
    if (i < NN) rowptr[i] += boff[blockIdx.x];
    if (i == 0) rowptr[NN] = ESL;
}

// ---- scatter: permute src + edge_attr(bf16) into CSR order ----
__global__ void k_scatter(const int* __restrict__ src, const int* __restrict__ dst,
                          const float* __restrict__ eattr,
                          const int* __restrict__ rowptr, int* __restrict__ cursor,
                          int* __restrict__ src_perm, ushort* __restrict__ eap) {
    int e = blockIdx.x * blockDim.x + threadIdx.x;
    if (e >= NE) return;
    int d = dst[e];
    int pos = atomicAdd(&cursor[d], 1);
    int idx = rowptr[d] + pos;
    src_perm[idx] = src[e];
    const float4* p4 = (const float4*)&eattr[(size_t)e * DE];
    float4 c0 = p4[0], c1 = p4[1], c2 = p4[2], c3 = p4[3];
    short8 r0, r1;
    r0[0]=f2bf(c0.x); r0[1]=f2bf(c0.y); r0[2]=f2bf(c0.z); r0[3]=f2bf(c0.w);
    r0[4]=f2bf(c1.x); r0[5]=f2bf(c1.y); r0[6]=f2bf(c1.z); r0[7]=f2bf(c1.w);
    r1[0]=f2bf(c2.x); r1[1]=f2bf(c2.y); r1[2]=f2bf(c2.z); r1[3]=f2bf(c2.w);
    r1[4]=f2bf(c3.x); r1[5]=f2bf(c3.y); r1[6]=f2bf(c3.z); r1[7]=f2bf(c3.w);
    short8* q = (short8*)&eap[(size_t)idx * DE];
    q[0] = r0; q[1] = r1;
}

// ---- self-loop mean attr -> written into the CSR self slot ----
__global__ void k_loop_csr(const int* __restrict__ rowptr,
                           ushort* __restrict__ eap, int* __restrict__ src_perm) {
    int wave = threadIdx.x >> 6, lane = threadIdx.x & 63;
    int d = blockIdx.x * 4 + wave;
    if (d >= NN) return;
    int j = lane & 15, g = lane >> 4;
    int kb = rowptr[d], ke1 = rowptr[d + 1] - 1;   // real edges in [kb, ke1)
    float sum = 0.f;
    for (int k = kb + g; k < ke1; k += 4)
        sum += bf2f(eap[(size_t)k * DE + j]);
    sum += __shfl_xor(sum, 16);
    sum += __shfl_xor(sum, 32);
    if (lane < 16)
        eap[(size_t)ke1 * DE + lane] = f2bf(sum / fmaxf((float)(ke1 - kb), 1.0f));
    if (lane == 16) src_perm[ke1] = d;
}

// ---- node linear transforms: xl(bf16) = x@Wl+bl, xr(fp32) = x@Wr+br ----
template<int DINT>
__global__ void k_lin(const float* __restrict__ x,
                      const float* __restrict__ Wl, const float* __restrict__ bl,
                      const float* __restrict__ Wr, const float* __restrict__ br,
                      ushort* __restrict__ xlb, float* __restrict__ xr) {
    int i0 = blockIdx.x * NPB;
    int t = threadIdx.x;
    int c = t & (C - 1);
    const float* W = (t < C) ? Wl : Wr;
    float bb = (t < C) ? bl[c] : br[c];
    float acc[NPB];
#pragma unroll
    for (int n = 0; n < NPB; ++n) acc[n] = bb;
    for (int k = 0; k < DINT; ++k) {
        float wk = W[k * C + c];
#pragma unroll
        for (int n = 0; n < NPB; ++n)
            acc[n] = fmaf(x[(i0 + n) * DINT + k], wk, acc[n]);
    }
    if (t < C) {
#pragma unroll
        for (int n = 0; n < NPB; ++n)
            xlb[(size_t)(i0 + n) * C + c] = f2bf(acc[n]);
    } else {
#pragma unroll
        for (int n = 0; n < NPB; ++n)
            xr[(size_t)(i0 + n) * C + c] = acc[n];
    }
}

// ---- fused GAT layer, 4-edge x 16-lane layout ----
// One wave per dst node. lane = g*16+l: group g handles edge k+g, lane l owns
// channels 4l..4l+3. We column-slice (16x4 fp32) lives in 64 VGPRs, loaded once.
// No running-max (softmax shift-invariant, logits << 88).
template<int DO_ELU, int OUT_BF16>
__global__ __launch_bounds__(64, 4) void k_gat(
        const int* __restrict__ src_perm, const int* __restrict__ rowptr,
        const ushort* __restrict__ eap,
        const ushort* __restrict__ xlb, const float* __restrict__ xr,
        const float* __restrict__ We, const float* __restrict__ att,
        const float* __restrict__ bias, void* __restrict__ o_) {
    int d = blockIdx.x;
    int lane = threadIdx.x;
    int g = lane >> 4, l = lane & 15;
    int c0 = l * 4;
    // per-lane We slice: We[j][c0..c0+3], j = 0..15  (64 VGPRs, loop-invariant)
    float wreg[DE][4];
#pragma unroll
    for (int j = 0; j < DE; ++j) {
        float4 wv = *(const float4*)&We[j * C + c0];
        wreg[j][0] = wv.x; wreg[j][1] = wv.y; wreg[j][2] = wv.z; wreg[j][3] = wv.w;
    }
    float4 av4 = *(const float4*)&att[c0];
    float attv[4] = {av4.x, av4.y, av4.z, av4.w};
    float4 xr4 = *(const float4*)&xr[(size_t)d * C + c0];
    float xrv[4] = {xr4.x, xr4.y, xr4.z, xr4.w};

    float l_run = 0.f, n_run[4] = {0.f, 0.f, 0.f, 0.f};
    int kb = rowptr[d], ke = rowptr[d + 1];
    for (int k = kb; k < ke; k += 4) {
        int kk = k + g;
        bool valid = kk < ke;
        int kidx = valid ? kk : (ke - 1);
        int s = src_perm[kidx];
        // xl channels c0..c0+3 (bf16, 8B); 16 lanes cover the full 128B row
        uint2 xlr = *(const uint2*)&xlb[(size_t)s * C + c0];
        float xlv[4] = {bflo(xlr.x), bfhi(xlr.x), bflo(xlr.y), bfhi(xlr.y)};
        // edge attr row (bf16, 32B broadcast within group; groups are seq rows)
        const uint4* ep = (const uint4*)&eap[(size_t)kidx * DE];
        uint4 e0 = ep[0], e1 = ep[1];
        float m[4];
#pragma unroll
        for (int i = 0; i < 4; ++i) m[i] = xlv[i] + xrv[i];
        unsigned ew[8] = {e0.x, e0.y, e0.z, e0.w, e1.x, e1.y, e1.z, e1.w};
#pragma unroll
        for (int wji = 0; wji < 8; ++wji) {
            float elo = bflo(ew[wji]), ehi = bfhi(ew[wji]);
#pragma unroll
            for (int i = 0; i < 4; ++i) {
                m[i] = fmaf(elo, wreg[2 * wji][i], m[i]);
                m[i] = fmaf(ehi, wreg[2 * wji + 1][i], m[i]);
            }
        }
        // leaky_relu + dot with att over this lane's 4 channels
        float p = 0.f;
#pragma unroll
        for (int i = 0; i < 4; ++i) {
            float t = fmaxf(m[i], NEGS * m[i]);   // leaky via max
            p = fmaf(t, attv[i], p);
        }
        // reduce across the 16 lanes of the group
        p += __shfl_xor(p, 1);
        p += __shfl_xor(p, 2);
        p += __shfl_xor(p, 4);
        p += __shfl_xor(p, 8);
        float pe = valid ? __expf(p) : 0.f;
        l_run += pe;
#pragma unroll
        for (int i = 0; i < 4; ++i) n_run[i] = fmaf(pe, xlv[i], n_run[i]);
    }
    // cross-group reduction (4 groups -> total)
    l_run += __shfl_xor(l_run, 16);
    l_run += __shfl_xor(l_run, 32);
#pragma unroll
    for (int i = 0; i < 4; ++i) {
        n_run[i] += __shfl_xor(n_run[i], 16);
        n_run[i] += __shfl_xor(n_run[i], 32);
    }
    if (g == 0) {
        float4 bv = *(const float4*)&bias[c0];
        float bvv[4] = {bv.x, bv.y, bv.z, bv.w};
        float res[4];
#pragma unroll
        for (int i = 0; i < 4; ++i) {
            float v = n_run[i] / l_run + bvv[i];
            if (DO_ELU) v = (v > 0.f) ? v : (__expf(v) - 1.0f);
            res[i] = v;
        }
        if (OUT_BF16) {
            uint2 pk;
            pk.x = (unsigned)f2bf(res[0]) | ((unsigned)f2bf(res[1]) << 16);
            pk.y = (unsigned)f2bf(res[2]) | ((unsigned)f2bf(res[3]) << 16);
            *(uint2*)&((ushort*)o_)[(size_t)d * C + c0] = pk;
        } else {
            float4 pk = {res[0], res[1], res[2], res[3]};
            *(float4*)&((float*)o_)[(size_t)d * C + c0] = pk;
        }
    }
}

// Cw1 [144][256] fp32 -> Cw1T bf16 [256][160] (transpose + zero-pad K)
__global__ void k_cvt_w(const float* __restrict__ Cw1, short* __restrict__ Cw1T) {
    int n = blockIdx.x;
    int k = threadIdx.x;
    Cw1T[n * KP + k] = (k < DCLS) ? (short)f2bf(Cw1[k * HID + n]) : (short)0;
}

// ---- MFMA edge classifier, transposed orientation + swizzled LDS ----
// D[m=hidden][n=edge] = sum_k Cw1T[m][k] * EF[n][k].
// sEF[64][128] holds h2b[src]|h2b[dst] per edge, XOR-swizzled: 16B chunk cc
// stored at (cc ^ (row&7)) -> ds_read_b128 at fixed column hits 8 bank
// groups (2-way = free) instead of the old ~16-way pattern.
// eattr (k 128..143) lives in a separate 2 KB sEA; k 144..159 is zero pad.
// LDS total 19456 B -> 8 blocks/CU theoretical (was 22528 -> 7).
__global__ __launch_bounds__(256, 4) void k_cls_mfma(
        const int* __restrict__ src, const int* __restrict__ dst,
        const float* __restrict__ eattr, const short* __restrict__ h2b,
        const short* __restrict__ Cw1T, const float* __restrict__ Cb1,
        const float* __restrict__ Cw2, const float* __restrict__ Cb2,
        float* __restrict__ out) {
    __shared__ short sEF[64 * 128];   // 16 KB, swizzled
    __shared__ short sEA[64 * 16];    // 2 KB
    __shared__ float sOutW[4][64];    // 1 KB
    int t = threadIdx.x;
    int ebase = blockIdx.x * 64;
    {
        int el = t & 63, part = t >> 6;
        int e = ebase + el;
        int swz = el & 7;
        if (part == 0) {          // src row -> chunks 0..7
            const short8* p = (const short8*)&h2b[(size_t)src[e] * C];
#pragma unroll
            for (int i = 0; i < 8; ++i)
                *(short8*)&sEF[el * 128 + ((i ^ swz) << 3)] = p[i];
        } else if (part == 1) {   // dst row -> chunks 8..15
            const short8* p = (const short8*)&h2b[(size_t)dst[e] * C];
#pragma unroll
            for (int i = 0; i < 8; ++i)
                *(short8*)&sEF[el * 128 + (((8 + i) ^ swz) << 3)] = p[i];
        } else if (part == 2) {   // eattr dims 0..7
            const float4* p4 = (const float4*)&eattr[(size_t)e * DE];
            float4 c0 = p4[0], c1 = p4[1];
            short8 r0;
            r0[0]=f2bf(c0.x); r0[1]=f2bf(c0.y); r0[2]=f2bf(c0.z); r0[3]=f2bf(c0.w);
            r0[4]=f2bf(c1.x); r0[5]=f2bf(c1.y); r0[6]=f2bf(c1.z); r0[7]=f2bf(c1.w);
            *(short8*)&sEA[el * 16] = r0;
        } else {                  // eattr dims 8..15
            const float4* p4 = (const float4*)&eattr[(size_t)e * DE];
            float4 c2 = p4[2], c3 = p4[3];
            short8 r1;
            r1[0]=f2bf(c2.x); r1[1]=f2bf(c2.y); r1[2]=f2bf(c2.z); r1[3]=f2bf(c2.w);
            r1[4]=f2bf(c3.x); r1[5]=f2bf(c3.y); r1[6]=f2bf(c3.z); r1[7]=f2bf(c3.w);
            *(short8*)&sEA[el * 16 + 8] = r1;
        }
    }
    __syncthreads();

    int lane = t & 63, wave = t >> 6;
    int l15 = lane & 15, quad = lane >> 4;
    int hb = wave * 64;                         // this wave's hidden base

    // bias + layer-2 weights for this lane's 16 hidden rows (r-contiguous)
    float cb1v[4][4], cw2v[4][4];
#pragma unroll
    for (int mt = 0; mt < 4; ++mt) {
        float4 bv = *(const float4*)&Cb1[hb + mt * 16 + quad * 4];
        float4 wv = *(const float4*)&Cw2[hb + mt * 16 + quad * 4];
        cb1v[mt][0] = bv.x; cb1v[mt][1] = bv.y; cb1v[mt][2] = bv.z; cb1v[mt][3] = bv.w;
        cw2v[mt][0] = wv.x; cw2v[mt][1] = wv.y; cw2v[mt][2] = wv.z; cw2v[mt][3] = wv.w;
    }

    f32x4 acc[4][4];
#pragma unroll
    for (int mt = 0; mt < 4; ++mt) {
        f32x4 bi = {cb1v[mt][0], cb1v[mt][1], cb1v[mt][2], cb1v[mt][3]};
#pragma unroll
        for (int nt = 0; nt < 4; ++nt) acc[mt][nt] = bi;   // bias folded into C-init
    }

    const short8* Ap = (const short8*)Cw1T;
#pragma unroll
    for (int kk = 0; kk < 5; ++kk) {
        short8 a[4], b[4];
#pragma unroll
        for (int mt = 0; mt < 4; ++mt)       // A: Cw1T rows = hidden (global, L2-hot)
            a[mt] = Ap[(hb + mt * 16 + l15) * 20 + kk * 4 + quad];
        if (kk < 4) {                        // B: h2b features from swizzled LDS
#pragma unroll
            for (int nt = 0; nt < 4; ++nt) {
                int r = nt * 16 + l15;
                b[nt] = *(const short8*)&sEF[r * 128 + (((kk * 4 + quad) ^ (r & 7)) << 3)];
            }
        } else {                             // B: eattr (quad<2) | K-pad zeros
            short8 z = {0, 0, 0, 0, 0, 0, 0, 0};
#pragma unroll
            for (int nt = 0; nt < 4; ++nt) {
                int r = nt * 16 + l15;
                b[nt] = (quad < 2) ? *(const short8*)&sEA[r * 16 + quad * 8] : z;
            }
        }
#pragma unroll
        for (int mt = 0; mt < 4; ++mt)
#pragma unroll
            for (int nt = 0; nt < 4; ++nt)
                acc[mt][nt] = __builtin_amdgcn_mfma_f32_16x16x32_bf16(
                    a[mt], b[nt], acc[mt][nt], 0, 0, 0);
    }

    // layer 2: out[edge] = sum_hid elu(h[hid][edge]) * cw2[hid]  (lane-local fma)
    float p[4] = {0.f, 0.f, 0.f, 0.f};
#pragma unroll
    for (int nt = 0; nt < 4; ++nt)
#pragma unroll
        for (int mt = 0; mt < 4; ++mt)
#pragma unroll
            for (int r = 0; r < 4; ++r) {
                float h = acc[mt][nt][r];                    // bias already in
                float act = (h > 0.f) ? h : (__expf(h) - 1.0f);  // fast elu
                p[nt] = fmaf(act, cw2v[mt][r], p[nt]);
            }
    // sum the 4 quads (hidden sub-ranges) -> full 64-hid partial for this wave
#pragma unroll
    for (int nt = 0; nt < 4; ++nt) {
        p[nt] += __shfl_xor(p[nt], 16);
        p[nt] += __shfl_xor(p[nt], 32);
    }
    if (quad == 0) {
#pragma unroll
        for (int nt = 0; nt < 4; ++nt)
            sOutW[wave][nt * 16 + l15] = p[nt];
    }
    __syncthreads();
    if (t < 64)
        out[ebase + t] = sOutW[0][t] + sOutW[1][t] + sOutW[2][t] + sOutW[3][t] + Cb2[0];
}

extern "C" void kernel_launch(void* const* d_in, const int* in_sizes, int n_in,
                              void* d_out, int out_size, void* d_ws, size_t ws_size,
                              hipStream_t stream) {
    const float* x     = (const float*)d_in[0];
    const float* eattr = (const float*)d_in[1];
    const float* W1l   = (const float*)d_in[2];
    const float* b1l   = (const float*)d_in[3];
    const float* W1r   = (const float*)d_in[4];
    const float* b1r   = (const float*)d_in[5];
    const float* We1   = (const float*)d_in[6];
    const float* att1  = (const float*)d_in[7];
    const float* bias1 = (const float*)d_in[8];
    const float* W2l   = (const float*)d_in[9];
    const float* b2l   = (const float*)d_in[10];
    const float* W2r   = (const float*)d_in[11];
    const float* b2r   = (const float*)d_in[12];
    const float* We2   = (const float*)d_in[13];
    const float* att2  = (const float*)d_in[14];
    const float* bias2 = (const float*)d_in[15];
    // d_in[16..19] (Aw1,Ab1,Aw2,Ab2) dead: softmax over size-1 axis == 1.0
    const float* Cw1   = (const float*)d_in[20];
    const float* Cb1   = (const float*)d_in[21];
    const float* Cw2   = (const float*)d_in[22];
    const float* Cb2   = (const float*)d_in[23];
    const int*   eidx  = (const int*)d_in[24];
    const int* src = eidx;
    const int* dst = eidx + NE;
    float* out = (float*)d_out;

    // workspace layout
    int*    deg      = (int*)d_ws;                     // NN
    int*    cursor   = deg + NN;                       // NN
    int*    rowptr   = cursor + NN;                    // NN+4
    int*    bsum     = rowptr + NN + 4;                // 256
    int*    boff     = bsum + 256;                     // 256
    int*    src_perm = boff + 256;                     // ESL
    ushort* eap      = (ushort*)(src_perm + ESL);      // ESL*16 bf16 (CSR-ordered eattr)
    ushort* xlb      = eap + (size_t)ESL * DE;         // 64NN bf16
    float*  xr       = (float*)(xlb + (size_t)NN * C); // 64NN
    float*  o1       = xr + (size_t)64 * NN;           // 64NN
    short*  h2b      = (short*)(o1 + (size_t)64 * NN); // 64NN bf16
    short*  cw1t     = h2b + (size_t)NN * C;           // 256*160 bf16

    // zero deg + cursor (contiguous)
    hipMemsetAsync(deg, 0, (size_t)(2 * NN) * sizeof(int), stream);

    // CSR build (with one self-loop slot per node)
    k_deg<<<(NE + 255) / 256, 256, 0, stream>>>(dst, deg);
    k_scan1<<<NBLK, 256, 0, stream>>>(deg, rowptr, bsum);
    k_scan2<<<1, 256, 0, stream>>>(bsum, boff);
    k_scan3<<<NBLK, 256, 0, stream>>>(rowptr, boff);
    k_scatter<<<(NE + 255) / 256, 256, 0, stream>>>(src, dst, eattr, rowptr, cursor,
                                                    src_perm, eap);
    k_loop_csr<<<(NN + 3) / 4, 256, 0, stream>>>(rowptr, eap, src_perm);

    // classifier weight conversion (independent)
    k_cvt_w<<<HID, KP, 0, stream>>>(Cw1, cw1t);

    // ---- GAT layer 1 ----
    k_lin<DIN1><<<NN / NPB, 128, 0, stream>>>(x, W1l, b1l, W1r, b1r, xlb, xr);
    k_gat<1, 0><<<NN, 64, 0, stream>>>(src_perm, rowptr, eap, xlb, xr,
                                       We1, att1, bias1, o1);   // -> h (elu, fp32)

    // ---- GAT layer 2 (h2 written directly as bf16) ----
    k_lin<C><<<NN / NPB, 128, 0, stream>>>(o1, W2l, b2l, W2r, b2r, xlb, xr);
    k_gat<0, 1><<<NN, 64, 0, stream>>>(src_perm, rowptr, eap, xlb, xr,
                                       We2, att2, bias2, h2b);  // -> h2 bf16

    // ---- MFMA edge classifier on original edges ----
    k_cls_mfma<<<NE / 64, 256, 0, stream>>>(src, dst, eattr, h2b, cw1t, Cb1, Cw2, Cb2, out);
}